// Round 1
// 3549.832 us; speedup vs baseline: 1.4595x; 1.4595x over previous
//
#include <hip/hip_runtime.h>
#include <hip/hip_bf16.h>
#include <cstdint>
#include <cstddef>

// LSTM encoder: B=64, T=512, D=256, UNITS=1024, gates G=4096 (i|f|g|o).
// z_t = x_t @ W + h_{t-1} @ U + b -> gates -> c,h.  Fused K = 1024(U) + 256(W).
// Persistent: 256 WGs, WG owns 4 units. Cross-WG traffic via relaxed agent-scope
// (sc0 sc1 bypass) accesses; ordering via s_waitcnt(0) + per-WG flags.
// R4: (a) h@U loads = 32x16B asm global_load_dwordx4 sc0 sc1, all issued
//     back-to-back, staged vmcnt(24/16/8/0) -> ~1 L3 RT instead of 4+ serialized
//     (old kernel had VGPR_Count=68, couldn't pipeline).
//     (b) weights live in VGPRs for the whole kernel (640B/lane) -> no LDS reads
//     on the MFMA critical path; wlds removed.
//     (c) h-store packed to 8B/thread (half the store acks before waitcnt(0)).

#define NWG    256
#define KSTEPS 40
#define SEQ_N  33554432    // 64*512*1024

typedef __attribute__((ext_vector_type(8))) short short8;
typedef __attribute__((ext_vector_type(4))) float floatx4;

static __device__ __forceinline__ short f2bf(float f) {
  __hip_bfloat16 h = __float2bfloat16(f);
  return *reinterpret_cast<short*>(&h);
}
static __device__ __forceinline__ float sigm(float x) { return 1.f / (1.f + __expf(-x)); }
static __device__ __forceinline__ float tanh_fast(float x) {
  float xc = fminf(fmaxf(x, -15.f), 15.f);
  float e  = __expf(2.f * xc);
  return (e - 1.f) / (e + 1.f);
}

// ---- prep: pack [U;W] into per-WG MFMA B-fragment order, bf16 ----
__global__ void pack_weights(const float* __restrict__ W, const float* __restrict__ U,
                             short* __restrict__ upack) {
  int idx  = blockIdx.x * 256 + threadIdx.x;   // 0 .. 256*40*64-1
  int lane = idx & 63;
  int kk   = (idx >> 6) % KSTEPS;
  int wg   = idx / (KSTEPS * 64);
  int quad = lane >> 4, n = lane & 15;
  int col  = (n >> 2) * 1024 + wg * 4 + (n & 3);
  int k0   = kk * 32 + quad * 8;
  short8 v;
#pragma unroll
  for (int j = 0; j < 8; ++j) {
    int k = k0 + j;
    float f = (k < 1024) ? U[(size_t)k * 4096 + col] : W[(size_t)(k - 1024) * 4096 + col];
    v[j] = f2bf(f);
  }
  *reinterpret_cast<short8*>(upack + (size_t)idx * 8) = v;
}

__global__ void convert_x(const float* __restrict__ x, short* __restrict__ xbf) {
  int idx = blockIdx.x * 256 + threadIdx.x;
  const float* xp = x + (size_t)idx * 8;
  short8 v;
#pragma unroll
  for (int j = 0; j < 8; ++j) v[j] = f2bf(xp[j]);
  *reinterpret_cast<short8*>(xbf + (size_t)idx * 8) = v;
}

// zero h0 + flags AT THE COHERENCE POINT (bypassing stores), so the
// persistent kernel's bypassing loads can't see stale poison.
__global__ void init_state(unsigned int* __restrict__ hbuf32,
                           int* __restrict__ arrive) {
  int idx = blockIdx.x * 256 + threadIdx.x;    // 288 blocks
  if (idx < 65536)
    __hip_atomic_store(&hbuf32[idx], 0u, __ATOMIC_RELAXED, __HIP_MEMORY_SCOPE_AGENT);
  else
    __hip_atomic_store(&arrive[idx - 65536], 0, __ATOMIC_RELAXED, __HIP_MEMORY_SCOPE_AGENT);
}

// 16B load that bypasses L1+L2 (reads the coherence point, like a relaxed
// agent-scope atomic but full dwordx4 width). Volatile asm keeps issue order.
#define HL(J, OFF)                                                          \
  asm volatile("global_load_dwordx4 %0, %1, off offset:" #OFF " sc0 sc1"    \
               : "=v"(hfrag[J]) : "v"(hb));

// staged wait: rule-18 analog -- sched_barrier(0) so MFMAs can't hoist above.
#define WAITVM(N)                                        \
  asm volatile("s_waitcnt vmcnt(" #N ")" ::: "memory");  \
  __builtin_amdgcn_sched_barrier(0);

#define MG(I)                                                                        \
  acc0 = __builtin_amdgcn_mfma_f32_16x16x32_bf16(hfrag[2*(I)],   wU[2*(I)],   acc0, 0, 0, 0); \
  acc1 = __builtin_amdgcn_mfma_f32_16x16x32_bf16(hfrag[2*(I)+1], wU[2*(I)+1], acc1, 0, 0, 0);

// ---- persistent stepper ----
__global__ __launch_bounds__(256, 1) void lstm_persist(
    const short* __restrict__ xbf,            // [64][512][256] bf16
    const short* __restrict__ upack,          // packed B frags, 20480 shorts/WG
    const float* __restrict__ bias,           // [4096] f32
    unsigned long long* __restrict__ hbuf64,  // [2][64][1024] bf16 as ull
    int* __restrict__ arrive,                 // [256*32] padded flag slots
    float* __restrict__ out)
{
  __shared__ float zlds[64 * 17];

  const int wg   = blockIdx.x;
  const int tid  = threadIdx.x;
  const int wave = tid >> 6;
  const int lane = tid & 63;
  const int quad = lane >> 4;
  const int l15  = lane & 15;
  const int arow = wave * 16 + l15;          // A-operand batch row
  const int eb   = tid >> 2;                 // elementwise batch
  const int ej   = tid & 3;                  // elementwise unit-in-wg
  const int unit = wg * 4 + ej;
  const float bi = bias[unit];
  const float bf = bias[1024 + unit];
  const float bg = bias[2048 + unit];
  const float bo = bias[3072 + unit];
  float creg = 0.f;

  // ---- weights resident in VGPRs for the whole kernel (640B/lane) ----
  short8 wU[32];   // h@U B-frags, ksteps 0..31 (K=1024)
  short8 wX[8];    // x@W B-frags, ksteps 32..39 (K=256)
  {
    const short* wsrc = upack + (size_t)wg * 20480 + lane * 8;
#pragma unroll
    for (int s = 0; s < 32; ++s)
      wU[s] = *reinterpret_cast<const short8*>(wsrc + s * 512);
#pragma unroll
    for (int s = 0; s < 8; ++s)
      wX[s] = *reinterpret_cast<const short8*>(wsrc + (32 + s) * 512);
  }

  const short* xrow = xbf + (size_t)arow * 512 * 256 + quad * 8;
  int* myslot = arrive + tid * 32;

  auto compute_x = [&](int t, floatx4& a0o, floatx4& a1o) {
    floatx4 a0 = {0.f, 0.f, 0.f, 0.f};
    floatx4 a1 = {0.f, 0.f, 0.f, 0.f};
    const short* xp = xrow + t * 256;
#pragma unroll
    for (int it = 0; it < 4; ++it) {
      short8 av0 = *reinterpret_cast<const short8*>(xp);
      short8 av1 = *reinterpret_cast<const short8*>(xp + 32);
      xp += 64;
      a0 = __builtin_amdgcn_mfma_f32_16x16x32_bf16(av0, wX[2*it],   a0, 0, 0, 0);
      a1 = __builtin_amdgcn_mfma_f32_16x16x32_bf16(av1, wX[2*it+1], a1, 0, 0, 0);
    }
    a0o = a0; a1o = a1;
  };

  floatx4 xa0, xa1;
  compute_x(0, xa0, xa1);

  for (int t = 0; t < 512; ++t) {
    const unsigned long long* hsrc = hbuf64 + ((size_t)(t & 1) << 14);       // 16384 ull
    unsigned long long*       hdst = hbuf64 + ((size_t)((t + 1) & 1) << 14);

    // ---- h@U: issue ALL 32 16B bypass loads, then staged-wait MFMA chain ----
    // per-iteration i: hfrag[2i] = A rows (16B @ i*128), hfrag[2i+1] = @ +64.
    const char* hb = (const char*)hsrc + (size_t)arow * 2048 + quad * 16;
    short8 hfrag[32];
    HL(0,0)    HL(1,64)    HL(2,128)   HL(3,192)
    HL(4,256)  HL(5,320)   HL(6,384)   HL(7,448)
    HL(8,512)  HL(9,576)   HL(10,640)  HL(11,704)
    HL(12,768) HL(13,832)  HL(14,896)  HL(15,960)
    HL(16,1024) HL(17,1088) HL(18,1152) HL(19,1216)
    HL(20,1280) HL(21,1344) HL(22,1408) HL(23,1472)
    HL(24,1536) HL(25,1600) HL(26,1664) HL(27,1728)
    HL(28,1792) HL(29,1856) HL(30,1920) HL(31,1984)

    floatx4 acc0 = xa0, acc1 = xa1;
    WAITVM(24) MG(0)  MG(1)  MG(2)  MG(3)
    WAITVM(16) MG(4)  MG(5)  MG(6)  MG(7)
    WAITVM(8)  MG(8)  MG(9)  MG(10) MG(11)
    WAITVM(0)  MG(12) MG(13) MG(14) MG(15)
    acc0 = acc0 + acc1;

    // C layout: col = lane&15, row = quad*4 + r
#pragma unroll
    for (int r = 0; r < 4; ++r)
      zlds[(wave * 16 + quad * 4 + r) * 17 + l15] = acc0[r];
    __syncthreads();

    float zi = zlds[eb * 17 + 0  + ej] + bi;
    float zf = zlds[eb * 17 + 4  + ej] + bf;
    float zg = zlds[eb * 17 + 8  + ej] + bg;
    float zo = zlds[eb * 17 + 12 + ej] + bo;
    float ig = sigm(zi), fg = sigm(zf), gg = tanh_fast(zg), og = sigm(zo);
    float cn = fg * creg + ig * gg;
    creg = cn;
    float hn = og * tanh_fast(cn);

    // pack 4 bf16 (this WG's 4 units) into one 8B bypass store per batch row
    float hn1 = __shfl_xor(hn, 1);
    unsigned int p01 = (unsigned int)(unsigned short)f2bf(hn) |
                       ((unsigned int)(unsigned short)f2bf(hn1) << 16);
    unsigned int pother = __shfl_xor(p01, 2);
    if (ej == 0) {
      unsigned long long v = (unsigned long long)p01 |
                             ((unsigned long long)pother << 32);
      __hip_atomic_store(&hdst[(size_t)eb * 256 + wg], v,
                         __ATOMIC_RELAXED, __HIP_MEMORY_SCOPE_AGENT);
    }
    out[((size_t)eb * 512 + t) * 1024 + unit] = hn;
    if (t == 511) {
      out[(size_t)SEQ_N + eb * 1024 + unit] = hn;                 // h_last
      out[(size_t)SEQ_N + 65536 + eb * 1024 + unit] = cn;         // c_last
    }

    if (t < 511) {
      __atomic_signal_fence(__ATOMIC_SEQ_CST);
      __builtin_amdgcn_s_waitcnt(0);   // h stores at coherence point
      __atomic_signal_fence(__ATOMIC_SEQ_CST);
      __syncthreads();                 // whole WG's h stores done
      if (tid == 0)
        __hip_atomic_store(&arrive[wg * 32], t + 1, __ATOMIC_RELAXED,
                           __HIP_MEMORY_SCOPE_AGENT);
      compute_x(t + 1, xa0, xa1);      // hide x@W in the wait window
      while (__hip_atomic_load(myslot, __ATOMIC_RELAXED,
                               __HIP_MEMORY_SCOPE_AGENT) < t + 1) {
        __builtin_amdgcn_s_sleep(1);
      }
      __atomic_signal_fence(__ATOMIC_SEQ_CST);
      __syncthreads();                 // all 256 flags confirmed
    }
  }
}

extern "C" void kernel_launch(void* const* d_in, const int* in_sizes, int n_in,
                              void* d_out, int out_size, void* d_ws, size_t ws_size,
                              hipStream_t stream) {
  const float* x    = (const float*)d_in[0];
  const float* W    = (const float*)d_in[1];
  const float* U    = (const float*)d_in[2];
  const float* bias = (const float*)d_in[3];
  float* out = (float*)d_out;
  char* ws = (char*)d_ws;

  short* upack = (short*)ws;                      // 10,485,760 B
  short* xbf   = (short*)(ws + 10485760);         // 16,777,216 B
  unsigned long long* hbuf = (unsigned long long*)(ws + 27262976); // 262,144 B
  int* arrive  = (int*)(ws + 27525120);           //     32,768 B
  (void)in_sizes; (void)n_in; (void)out_size; (void)ws_size;

  init_state<<<288, 256, 0, stream>>>((unsigned int*)hbuf, arrive);
  pack_weights<<<2560, 256, 0, stream>>>(W, U, upack);
  convert_x<<<4096, 256, 0, stream>>>(x, xbf);
  lstm_persist<<<NWG, 256, 0, stream>>>(xbf, upack, bias, hbuf, arrive, out);
}

// Round 2
// 3407.196 us; speedup vs baseline: 1.5206x; 1.0419x over previous
//
#include <hip/hip_runtime.h>
#include <hip/hip_bf16.h>
#include <cstdint>
#include <cstddef>

// LSTM encoder: B=64, T=512, D=256, UNITS=1024, gates G=4096 (i|f|g|o).
// Persistent, 256 WGs x 128 threads. WG = (unit-group g8 = wg>>1: 8 units) x
// (row-half = wg&1: 32 batch rows). Halves the per-step h-broadcast traffic
// (32MB -> 16MB) AND per-CU read demand vs R1's 256x(4 units x 64 rows).
// Cross-WG h via relaxed agent-scope (sc0 sc1 bypass); ordering: waitcnt(0)+flags.
// Tile0 weights in VGPRs, tile1 in LDS (stride-16B ds_read_b128, conflict-free).
// out[] stores moved after the flag store (off the waitcnt(0) critical path).

#define NWG    256
#define KSTEPS 40
#define SEQ_N  33554432    // 64*512*1024

typedef __attribute__((ext_vector_type(8))) short short8;
typedef __attribute__((ext_vector_type(4))) float floatx4;
typedef __attribute__((ext_vector_type(2))) float floatx2;

static __device__ __forceinline__ short f2bf(float f) {
  __hip_bfloat16 h = __float2bfloat16(f);
  return *reinterpret_cast<short*>(&h);
}
static __device__ __forceinline__ float sigm(float x) { return 1.f / (1.f + __expf(-x)); }
static __device__ __forceinline__ float tanh_fast(float x) {
  float xc = fminf(fmaxf(x, -15.f), 15.f);
  float e  = __expf(2.f * xc);
  return (e - 1.f) / (e + 1.f);
}

// ---- prep: pack [U;W] into per-unit-group MFMA B-fragment order, bf16 ----
// upack[g8][ct][kk][lane][8]: g8=unit-group(8 units), ct=column tile(4 units).
__global__ void pack_weights(const float* __restrict__ W, const float* __restrict__ U,
                             short* __restrict__ upack) {
  int idx  = blockIdx.x * 256 + threadIdx.x;   // 0 .. 655359
  int lane = idx & 63;
  int kk   = (idx >> 6) % KSTEPS;
  int ct   = ((idx >> 6) / KSTEPS) & 1;
  int g8   = idx / (KSTEPS * 64 * 2);
  int quad = lane >> 4, n = lane & 15;
  int col  = (n >> 2) * 1024 + g8 * 8 + ct * 4 + (n & 3);
  int k0   = kk * 32 + quad * 8;
  short8 v;
#pragma unroll
  for (int j = 0; j < 8; ++j) {
    int k = k0 + j;
    float f = (k < 1024) ? U[(size_t)k * 4096 + col] : W[(size_t)(k - 1024) * 4096 + col];
    v[j] = f2bf(f);
  }
  *reinterpret_cast<short8*>(upack + (size_t)idx * 8) = v;
}

__global__ void convert_x(const float* __restrict__ x, short* __restrict__ xbf) {
  int idx = blockIdx.x * 256 + threadIdx.x;
  const float* xp = x + (size_t)idx * 8;
  short8 v;
#pragma unroll
  for (int j = 0; j < 8; ++j) v[j] = f2bf(xp[j]);
  *reinterpret_cast<short8*>(xbf + (size_t)idx * 8) = v;
}

// zero h0 + flags AT THE COHERENCE POINT (bypassing stores).
__global__ void init_state(unsigned int* __restrict__ hbuf32,
                           int* __restrict__ arrive) {
  int idx = blockIdx.x * 256 + threadIdx.x;    // 288 blocks
  if (idx < 65536)
    __hip_atomic_store(&hbuf32[idx], 0u, __ATOMIC_RELAXED, __HIP_MEMORY_SCOPE_AGENT);
  else
    __hip_atomic_store(&arrive[idx - 65536], 0, __ATOMIC_RELAXED, __HIP_MEMORY_SCOPE_AGENT);
}

// 16B load that bypasses L1+L2 (reads the coherence point). Volatile asm keeps order.
#define HL(J, OFF)                                                          \
  asm volatile("global_load_dwordx4 %0, %1, off offset:" #OFF " sc0 sc1"    \
               : "=v"(hfrag[J]) : "v"(hb));

#define WAITVM(N)                                        \
  asm volatile("s_waitcnt vmcnt(" #N ")" ::: "memory");  \
  __builtin_amdgcn_sched_barrier(0);

#define MG0(I)                                                                        \
  a00 = __builtin_amdgcn_mfma_f32_16x16x32_bf16(hfrag[2*(I)],   wU0[2*(I)],   a00, 0, 0, 0); \
  a01 = __builtin_amdgcn_mfma_f32_16x16x32_bf16(hfrag[2*(I)+1], wU0[2*(I)+1], a01, 0, 0, 0);

// ---- persistent stepper ----
__global__ __launch_bounds__(128, 1) void lstm_persist(
    const short* __restrict__ xbf,            // [64][512][256] bf16
    const short* __restrict__ upack,          // packed B frags, 40960 shorts/group
    const float* __restrict__ bias,           // [4096] f32
    unsigned long long* __restrict__ hbuf64,  // [2][64][1024] bf16 as ull
    int* __restrict__ arrive,                 // [256*32] padded flag slots
    float* __restrict__ out)
{
  __shared__ short wlds[20480];       // tile1 weights, 40KB
  __shared__ float zlds[32 * 36];     // 4.6KB gate staging

  const int wg   = blockIdx.x;
  const int g8   = wg >> 1;                  // unit group (8 units)
  const int half = wg & 1;                   // batch-row half (32 rows)
  const int tid  = threadIdx.x;              // 0..127
  const int wave = tid >> 6;                 // 0..1
  const int lane = tid & 63;
  const int quad = lane >> 4;
  const int l15  = lane & 15;
  const int arow = half * 32 + wave * 16 + l15;   // global batch row (A operand)
  const int eb   = tid >> 2;                 // local row 0..31 (elementwise)
  const int gr   = half * 32 + eb;           // global row
  const int q    = tid & 3;                  // owns units u0, u0+1
  const int u0   = g8 * 8 + q * 2;
  const float bi0 = bias[u0],        bi1 = bias[u0 + 1];
  const float bf0 = bias[1024 + u0], bf1 = bias[1025 + u0];
  const float bg0 = bias[2048 + u0], bg1 = bias[2049 + u0];
  const float bo0 = bias[3072 + u0], bo1 = bias[3073 + u0];
  float c0 = 0.f, c1 = 0.f;

  // ---- tile0 weights resident in VGPRs; tile1 staged to LDS ----
  const short* wsrc = upack + (size_t)g8 * 40960;
  short8 wU0[32];   // tile0 h@U, ksteps 0..31
  short8 wX0[8];    // tile0 x@W, ksteps 32..39
#pragma unroll
  for (int s = 0; s < 32; ++s)
    wU0[s] = *reinterpret_cast<const short8*>(wsrc + (s * 64 + lane) * 8);
#pragma unroll
  for (int s = 0; s < 8; ++s)
    wX0[s] = *reinterpret_cast<const short8*>(wsrc + ((32 + s) * 64 + lane) * 8);
  {
    const short* src1 = wsrc + 20480;
#pragma unroll
    for (int i = 0; i < 20; ++i) {
      int id = i * 128 + tid;
      *reinterpret_cast<short8*>(wlds + id * 8) =
          *reinterpret_cast<const short8*>(src1 + id * 8);
    }
  }
  __syncthreads();

  const short* xrow = xbf + (size_t)arow * 512 * 256 + quad * 8;
  int* slotA = arrive + tid * 32;            // flag of wg = tid
  int* slotB = arrive + (tid + 128) * 32;    // flag of wg = tid+128

  auto compute_x = [&](int t, floatx4& x00, floatx4& x01, floatx4& x10, floatx4& x11) {
    floatx4 a0 = {0.f,0.f,0.f,0.f}, a1 = a0, a2 = a0, a3 = a0;
    const short* xp = xrow + t * 256;
#pragma unroll
    for (int it = 0; it < 4; ++it) {
      short8 av0 = *reinterpret_cast<const short8*>(xp);
      short8 av1 = *reinterpret_cast<const short8*>(xp + 32);
      short8 b10 = *reinterpret_cast<const short8*>(wlds + ((32 + 2*it) * 64 + lane) * 8);
      short8 b11 = *reinterpret_cast<const short8*>(wlds + ((33 + 2*it) * 64 + lane) * 8);
      xp += 64;
      a0 = __builtin_amdgcn_mfma_f32_16x16x32_bf16(av0, wX0[2*it],   a0, 0, 0, 0);
      a1 = __builtin_amdgcn_mfma_f32_16x16x32_bf16(av1, wX0[2*it+1], a1, 0, 0, 0);
      a2 = __builtin_amdgcn_mfma_f32_16x16x32_bf16(av0, b10,         a2, 0, 0, 0);
      a3 = __builtin_amdgcn_mfma_f32_16x16x32_bf16(av1, b11,         a3, 0, 0, 0);
    }
    x00 = a0; x01 = a1; x10 = a2; x11 = a3;
  };

  floatx4 x00, x01, x10, x11;
  compute_x(0, x00, x01, x10, x11);

  for (int t = 0; t < 512; ++t) {
    const unsigned long long* hsrc = hbuf64 + ((size_t)(t & 1) << 14);
    unsigned long long*       hdst = hbuf64 + ((size_t)((t + 1) & 1) << 14);

    // ---- h@U: issue ALL 32 16B bypass loads, then staged-wait MFMA chain ----
    const char* hb = (const char*)hsrc + (size_t)arow * 2048 + quad * 16;
    short8 hfrag[32];
    asm volatile("s_waitcnt vmcnt(0)" ::: "memory");  // insurance: clean FIFO
    HL(0,0)     HL(1,64)    HL(2,128)   HL(3,192)
    HL(4,256)   HL(5,320)   HL(6,384)   HL(7,448)
    HL(8,512)   HL(9,576)   HL(10,640)  HL(11,704)
    HL(12,768)  HL(13,832)  HL(14,896)  HL(15,960)
    HL(16,1024) HL(17,1088) HL(18,1152) HL(19,1216)
    HL(20,1280) HL(21,1344) HL(22,1408) HL(23,1472)
    HL(24,1536) HL(25,1600) HL(26,1664) HL(27,1728)
    HL(28,1792) HL(29,1856) HL(30,1920) HL(31,1984)

    floatx4 a00 = x00, a01 = x01, a10 = x10, a11 = x11;
    WAITVM(24) MG0(0)  MG0(1)  MG0(2)  MG0(3)
    WAITVM(16) MG0(4)  MG0(5)  MG0(6)  MG0(7)
    WAITVM(8)  MG0(8)  MG0(9)  MG0(10) MG0(11)
    WAITVM(0)  MG0(12) MG0(13) MG0(14) MG0(15)
    // tile1: B from LDS (hfrags all resident now; ds_reads pipeline)
#pragma unroll
    for (int j = 0; j < 16; ++j) {
      short8 b0 = *reinterpret_cast<const short8*>(wlds + ((2*j)     * 64 + lane) * 8);
      short8 b1 = *reinterpret_cast<const short8*>(wlds + ((2*j + 1) * 64 + lane) * 8);
      a10 = __builtin_amdgcn_mfma_f32_16x16x32_bf16(hfrag[2*j],   b0, a10, 0, 0, 0);
      a11 = __builtin_amdgcn_mfma_f32_16x16x32_bf16(hfrag[2*j+1], b1, a11, 0, 0, 0);
    }
    a00 = a00 + a01;
    a10 = a10 + a11;

    // C layout: col = lane&15 (= gate*4+uit), row = quad*4 + r (local tile row)
#pragma unroll
    for (int r = 0; r < 4; ++r) {
      int zr = (wave * 16 + quad * 4 + r) * 36;
      zlds[zr + l15]      = a00[r];
      zlds[zr + 18 + l15] = a10[r];
    }
    __syncthreads();

    const float* zb = zlds + eb * 36 + (q >> 1) * 18 + (q & 1) * 2;
    float zi0 = zb[0]  + bi0, zi1 = zb[1]  + bi1;
    float zf0 = zb[4]  + bf0, zf1 = zb[5]  + bf1;
    float zg0 = zb[8]  + bg0, zg1 = zb[9]  + bg1;
    float zo0 = zb[12] + bo0, zo1 = zb[13] + bo1;
    float i0 = sigm(zi0), f0 = sigm(zf0), g0 = tanh_fast(zg0), o0 = sigm(zo0);
    float i1 = sigm(zi1), f1 = sigm(zf1), g1 = tanh_fast(zg1), o1 = sigm(zo1);
    c0 = f0 * c0 + i0 * g0;
    c1 = f1 * c1 + i1 * g1;
    float h0 = o0 * tanh_fast(c0);
    float h1 = o1 * tanh_fast(c1);

    // pack 4 bf16 (per lane-pair) -> one 8B bypass store per 4 units
    unsigned int p01 = (unsigned int)(unsigned short)f2bf(h0) |
                       ((unsigned int)(unsigned short)f2bf(h1) << 16);
    unsigned int pother = __shfl_xor(p01, 1);
    if ((q & 1) == 0) {
      unsigned long long v = (unsigned long long)p01 |
                             ((unsigned long long)pother << 32);
      __hip_atomic_store(&hdst[(size_t)gr * 256 + g8 * 2 + (q >> 1)], v,
                         __ATOMIC_RELAXED, __HIP_MEMORY_SCOPE_AGENT);
    }

    if (t < 511) {
      __atomic_signal_fence(__ATOMIC_SEQ_CST);
      __builtin_amdgcn_s_waitcnt(0);   // h stores at coherence point
      __atomic_signal_fence(__ATOMIC_SEQ_CST);
      __syncthreads();                 // whole WG's h stores done
      if (tid == 0)
        __hip_atomic_store(&arrive[wg * 32], t + 1, __ATOMIC_RELAXED,
                           __HIP_MEMORY_SCOPE_AGENT);
      // streaming output AFTER the flag: off the critical path
      {
        floatx2 hv = {h0, h1};
        *reinterpret_cast<floatx2*>(out + ((size_t)gr * 512 + t) * 1024 + u0) = hv;
      }
      compute_x(t + 1, x00, x01, x10, x11);   // hide x@W in the wait window
      while (__hip_atomic_load(slotA, __ATOMIC_RELAXED, __HIP_MEMORY_SCOPE_AGENT) < t + 1)
        __builtin_amdgcn_s_sleep(1);
      while (__hip_atomic_load(slotB, __ATOMIC_RELAXED, __HIP_MEMORY_SCOPE_AGENT) < t + 1)
        __builtin_amdgcn_s_sleep(1);
      __atomic_signal_fence(__ATOMIC_SEQ_CST);
      __syncthreads();                 // all 256 flags confirmed
    } else {
      floatx2 hv = {h0, h1};
      floatx2 cv = {c0, c1};
      *reinterpret_cast<floatx2*>(out + ((size_t)gr * 512 + 511) * 1024 + u0) = hv;
      *reinterpret_cast<floatx2*>(out + (size_t)SEQ_N + (size_t)gr * 1024 + u0) = hv;
      *reinterpret_cast<floatx2*>(out + (size_t)SEQ_N + 65536 + (size_t)gr * 1024 + u0) = cv;
    }
  }
}

extern "C" void kernel_launch(void* const* d_in, const int* in_sizes, int n_in,
                              void* d_out, int out_size, void* d_ws, size_t ws_size,
                              hipStream_t stream) {
  const float* x    = (const float*)d_in[0];
  const float* W    = (const float*)d_in[1];
  const float* U    = (const float*)d_in[2];
  const float* bias = (const float*)d_in[3];
  float* out = (float*)d_out;
  char* ws = (char*)d_ws;

  short* upack = (short*)ws;                      // 10,485,760 B
  short* xbf   = (short*)(ws + 10485760);         // 16,777,216 B
  unsigned long long* hbuf = (unsigned long long*)(ws + 27262976); // 262,144 B
  int* arrive  = (int*)(ws + 27525120);           //     32,768 B
  (void)in_sizes; (void)n_in; (void)out_size; (void)ws_size;

  init_state<<<288, 256, 0, stream>>>((unsigned int*)hbuf, arrive);
  pack_weights<<<2560, 256, 0, stream>>>(W, U, upack);
  convert_x<<<4096, 256, 0, stream>>>(x, xbf);
  lstm_persist<<<NWG, 128, 0, stream>>>(xbf, upack, bias, hbuf, arrive, out);
}

// Round 3
// 3194.235 us; speedup vs baseline: 1.6220x; 1.0667x over previous
//
#include <hip/hip_runtime.h>
#include <hip/hip_bf16.h>
#include <cstdint>
#include <cstddef>

// LSTM encoder: B=64, T=512, D=256, UNITS=1024, gates G=4096 (i|f|g|o).
// Persistent, 256 WGs x 128 threads. WG = (unit-group g8 = wg>>1: 8 units) x
// (row-half = wg&1: 32 batch rows).
// R3: sync rebuilt around 8 epoch counters. R1/R2 polled 256 padded flags from
// EVERY thread = ~65K DF requests per poll period -> fabric congestion inflating
// all RTs (explains why halving h traffic in R2 saved only 0.3us/step).
// Now: producers atomicAdd(+1) into counter[wg&7] (8 x 64B-padded, monotonic,
// target 32*(t+1)); only wave 0 polls (8 lanes, 8 requests/period). x-loads and
// out[] stores issue BEFORE waitcnt(0) (store-ack overlaps load latency); x@W
// MFMAs run between counter-add and poll.

#define NWG    256
#define KSTEPS 40
#define SEQ_N  33554432    // 64*512*1024

typedef __attribute__((ext_vector_type(8))) short short8;
typedef __attribute__((ext_vector_type(4))) float floatx4;
typedef __attribute__((ext_vector_type(2))) float floatx2;

static __device__ __forceinline__ short f2bf(float f) {
  __hip_bfloat16 h = __float2bfloat16(f);
  return *reinterpret_cast<short*>(&h);
}
static __device__ __forceinline__ float sigm(float x) { return 1.f / (1.f + __expf(-x)); }
static __device__ __forceinline__ float tanh_fast(float x) {
  float xc = fminf(fmaxf(x, -15.f), 15.f);
  float e  = __expf(2.f * xc);
  return (e - 1.f) / (e + 1.f);
}

// ---- prep: pack [U;W] into per-unit-group MFMA B-fragment order, bf16 ----
__global__ void pack_weights(const float* __restrict__ W, const float* __restrict__ U,
                             short* __restrict__ upack) {
  int idx  = blockIdx.x * 256 + threadIdx.x;   // 0 .. 655359
  int lane = idx & 63;
  int kk   = (idx >> 6) % KSTEPS;
  int ct   = ((idx >> 6) / KSTEPS) & 1;
  int g8   = idx / (KSTEPS * 64 * 2);
  int quad = lane >> 4, n = lane & 15;
  int col  = (n >> 2) * 1024 + g8 * 8 + ct * 4 + (n & 3);
  int k0   = kk * 32 + quad * 8;
  short8 v;
#pragma unroll
  for (int j = 0; j < 8; ++j) {
    int k = k0 + j;
    float f = (k < 1024) ? U[(size_t)k * 4096 + col] : W[(size_t)(k - 1024) * 4096 + col];
    v[j] = f2bf(f);
  }
  *reinterpret_cast<short8*>(upack + (size_t)idx * 8) = v;
}

__global__ void convert_x(const float* __restrict__ x, short* __restrict__ xbf) {
  int idx = blockIdx.x * 256 + threadIdx.x;
  const float* xp = x + (size_t)idx * 8;
  short8 v;
#pragma unroll
  for (int j = 0; j < 8; ++j) v[j] = f2bf(xp[j]);
  *reinterpret_cast<short8*>(xbf + (size_t)idx * 8) = v;
}

// zero h0 + counters AT THE COHERENCE POINT (bypassing stores).
__global__ void init_state(unsigned int* __restrict__ hbuf32,
                           int* __restrict__ arrive) {
  int idx = blockIdx.x * 256 + threadIdx.x;    // 288 blocks
  if (idx < 65536)
    __hip_atomic_store(&hbuf32[idx], 0u, __ATOMIC_RELAXED, __HIP_MEMORY_SCOPE_AGENT);
  else
    __hip_atomic_store(&arrive[idx - 65536], 0, __ATOMIC_RELAXED, __HIP_MEMORY_SCOPE_AGENT);
}

// 16B load that bypasses L1+L2 (reads the coherence point). Volatile asm keeps order.
#define HL(J, OFF)                                                          \
  asm volatile("global_load_dwordx4 %0, %1, off offset:" #OFF " sc0 sc1"    \
               : "=v"(hfrag[J]) : "v"(hb));

#define WAITVM(N)                                        \
  asm volatile("s_waitcnt vmcnt(" #N ")" ::: "memory");  \
  __builtin_amdgcn_sched_barrier(0);

#define MG0(I)                                                                        \
  a00 = __builtin_amdgcn_mfma_f32_16x16x32_bf16(hfrag[2*(I)],   wU0[2*(I)],   a00, 0, 0, 0); \
  a01 = __builtin_amdgcn_mfma_f32_16x16x32_bf16(hfrag[2*(I)+1], wU0[2*(I)+1], a01, 0, 0, 0);

// ---- persistent stepper ----
__global__ __launch_bounds__(128, 1) void lstm_persist(
    const short* __restrict__ xbf,            // [64][512][256] bf16
    const short* __restrict__ upack,          // packed B frags, 40960 shorts/group
    const float* __restrict__ bias,           // [4096] f32
    unsigned long long* __restrict__ hbuf64,  // [2][64][1024] bf16 as ull
    int* __restrict__ arrive,                 // [0..127]: 8 counters @ 64B stride
    float* __restrict__ out)
{
  __shared__ short wlds[20480];       // tile1 weights, 40KB
  __shared__ float zlds[32 * 36];     // 4.6KB gate staging

  const int wg   = blockIdx.x;
  const int g8   = wg >> 1;                  // unit group (8 units)
  const int half = wg & 1;                   // batch-row half (32 rows)
  const int tid  = threadIdx.x;              // 0..127
  const int wave = tid >> 6;                 // 0..1
  const int lane = tid & 63;
  const int quad = lane >> 4;
  const int l15  = lane & 15;
  const int arow = half * 32 + wave * 16 + l15;   // global batch row (A operand)
  const int eb   = tid >> 2;                 // local row 0..31 (elementwise)
  const int gr   = half * 32 + eb;           // global row
  const int q    = tid & 3;                  // owns units u0, u0+1
  const int u0   = g8 * 8 + q * 2;
  const float bi0 = bias[u0],        bi1 = bias[u0 + 1];
  const float bf0 = bias[1024 + u0], bf1 = bias[1025 + u0];
  const float bg0 = bias[2048 + u0], bg1 = bias[2049 + u0];
  const float bo0 = bias[3072 + u0], bo1 = bias[3073 + u0];
  float c0 = 0.f, c1 = 0.f;

  // ---- tile0 weights resident in VGPRs; tile1 staged to LDS ----
  const short* wsrc = upack + (size_t)g8 * 40960;
  short8 wU0[32];   // tile0 h@U, ksteps 0..31
  short8 wX0[8];    // tile0 x@W, ksteps 32..39
#pragma unroll
  for (int s = 0; s < 32; ++s)
    wU0[s] = *reinterpret_cast<const short8*>(wsrc + (s * 64 + lane) * 8);
#pragma unroll
  for (int s = 0; s < 8; ++s)
    wX0[s] = *reinterpret_cast<const short8*>(wsrc + ((32 + s) * 64 + lane) * 8);
  {
    const short* src1 = wsrc + 20480;
#pragma unroll
    for (int i = 0; i < 20; ++i) {
      int id = i * 128 + tid;
      *reinterpret_cast<short8*>(wlds + id * 8) =
          *reinterpret_cast<const short8*>(src1 + id * 8);
    }
  }
  __syncthreads();

  const short* xrow = xbf + (size_t)arow * 512 * 256 + quad * 8;

  short8 xv[8];                              // prefetched x A-frags
  auto load_x = [&](int t) {
    const short* xp = xrow + t * 256;
#pragma unroll
    for (int it = 0; it < 4; ++it) {
      xv[2*it]   = *reinterpret_cast<const short8*>(xp);
      xv[2*it+1] = *reinterpret_cast<const short8*>(xp + 32);
      xp += 64;
    }
  };
  auto mfma_x = [&](floatx4& x00, floatx4& x01, floatx4& x10, floatx4& x11) {
    floatx4 a0 = {0.f,0.f,0.f,0.f}, a1 = a0, a2 = a0, a3 = a0;
#pragma unroll
    for (int it = 0; it < 4; ++it) {
      short8 b10 = *reinterpret_cast<const short8*>(wlds + ((32 + 2*it) * 64 + lane) * 8);
      short8 b11 = *reinterpret_cast<const short8*>(wlds + ((33 + 2*it) * 64 + lane) * 8);
      a0 = __builtin_amdgcn_mfma_f32_16x16x32_bf16(xv[2*it],   wX0[2*it],   a0, 0, 0, 0);
      a1 = __builtin_amdgcn_mfma_f32_16x16x32_bf16(xv[2*it+1], wX0[2*it+1], a1, 0, 0, 0);
      a2 = __builtin_amdgcn_mfma_f32_16x16x32_bf16(xv[2*it],   b10,         a2, 0, 0, 0);
      a3 = __builtin_amdgcn_mfma_f32_16x16x32_bf16(xv[2*it+1], b11,         a3, 0, 0, 0);
    }
    x00 = a0; x01 = a1; x10 = a2; x11 = a3;
  };

  floatx4 x00, x01, x10, x11;
  load_x(0);
  mfma_x(x00, x01, x10, x11);

  for (int t = 0; t < 512; ++t) {
    const unsigned long long* hsrc = hbuf64 + ((size_t)(t & 1) << 14);
    unsigned long long*       hdst = hbuf64 + ((size_t)((t + 1) & 1) << 14);

    // ---- h@U: issue ALL 32 16B bypass loads, then staged-wait MFMA chain ----
    const char* hb = (const char*)hsrc + (size_t)arow * 2048 + quad * 16;
    short8 hfrag[32];
    asm volatile("s_waitcnt vmcnt(0)" ::: "memory");  // clean FIFO for staged waits
    HL(0,0)     HL(1,64)    HL(2,128)   HL(3,192)
    HL(4,256)   HL(5,320)   HL(6,384)   HL(7,448)
    HL(8,512)   HL(9,576)   HL(10,640)  HL(11,704)
    HL(12,768)  HL(13,832)  HL(14,896)  HL(15,960)
    HL(16,1024) HL(17,1088) HL(18,1152) HL(19,1216)
    HL(20,1280) HL(21,1344) HL(22,1408) HL(23,1472)
    HL(24,1536) HL(25,1600) HL(26,1664) HL(27,1728)
    HL(28,1792) HL(29,1856) HL(30,1920) HL(31,1984)

    floatx4 a00 = x00, a01 = x01, a10 = x10, a11 = x11;
    WAITVM(24) MG0(0)  MG0(1)  MG0(2)  MG0(3)
    WAITVM(16) MG0(4)  MG0(5)  MG0(6)  MG0(7)
    WAITVM(8)  MG0(8)  MG0(9)  MG0(10) MG0(11)
    WAITVM(0)  MG0(12) MG0(13) MG0(14) MG0(15)
    // tile1: B from LDS (hfrags all resident now)
#pragma unroll
    for (int j = 0; j < 16; ++j) {
      short8 b0 = *reinterpret_cast<const short8*>(wlds + ((2*j)     * 64 + lane) * 8);
      short8 b1 = *reinterpret_cast<const short8*>(wlds + ((2*j + 1) * 64 + lane) * 8);
      a10 = __builtin_amdgcn_mfma_f32_16x16x32_bf16(hfrag[2*j],   b0, a10, 0, 0, 0);
      a11 = __builtin_amdgcn_mfma_f32_16x16x32_bf16(hfrag[2*j+1], b1, a11, 0, 0, 0);
    }
    a00 = a00 + a01;
    a10 = a10 + a11;

    // C layout: col = lane&15 (= gate*4+uit), row = quad*4 + r (local tile row)
#pragma unroll
    for (int r = 0; r < 4; ++r) {
      int zr = (wave * 16 + quad * 4 + r) * 36;
      zlds[zr + l15]      = a00[r];
      zlds[zr + 18 + l15] = a10[r];
    }
    __syncthreads();

    const float* zb = zlds + eb * 36 + (q >> 1) * 18 + (q & 1) * 2;
    float zi0 = zb[0]  + bi0, zi1 = zb[1]  + bi1;
    float zf0 = zb[4]  + bf0, zf1 = zb[5]  + bf1;
    float zg0 = zb[8]  + bg0, zg1 = zb[9]  + bg1;
    float zo0 = zb[12] + bo0, zo1 = zb[13] + bo1;
    float i0 = sigm(zi0), f0 = sigm(zf0), g0 = tanh_fast(zg0), o0 = sigm(zo0);
    float i1 = sigm(zi1), f1 = sigm(zf1), g1 = tanh_fast(zg1), o1 = sigm(zo1);
    c0 = f0 * c0 + i0 * g0;
    c1 = f1 * c1 + i1 * g1;
    float h0 = o0 * tanh_fast(c0);
    float h1 = o1 * tanh_fast(c1);

    // pack 4 bf16 (per lane-pair) -> one 8B bypass store per 4 units
    unsigned int p01 = (unsigned int)(unsigned short)f2bf(h0) |
                       ((unsigned int)(unsigned short)f2bf(h1) << 16);
    unsigned int pother = __shfl_xor(p01, 1);
    if ((q & 1) == 0) {
      unsigned long long v = (unsigned long long)p01 |
                             ((unsigned long long)pother << 32);
      __hip_atomic_store(&hdst[(size_t)gr * 256 + g8 * 2 + (q >> 1)], v,
                         __ATOMIC_RELAXED, __HIP_MEMORY_SCOPE_AGENT);
    }

    if (t < 511) {
      // issue x prefetch + out store BEFORE the drain: their latency overlaps
      // the bypass store ack.
      load_x(t + 1);
      {
        floatx2 hv = {h0, h1};
        *reinterpret_cast<floatx2*>(out + ((size_t)gr * 512 + t) * 1024 + u0) = hv;
      }
      __atomic_signal_fence(__ATOMIC_SEQ_CST);
      __builtin_amdgcn_s_waitcnt(0);   // h stores (+x loads, out stores) drained
      __atomic_signal_fence(__ATOMIC_SEQ_CST);
      __syncthreads();                 // whole WG's h stores done
      if (tid == 0)
        __hip_atomic_fetch_add(&arrive[(wg & 7) * 16], 1,
                               __ATOMIC_RELAXED, __HIP_MEMORY_SCOPE_AGENT);
      mfma_x(x00, x01, x10, x11);      // pure VGPR/LDS: hides add propagation
      if (wave == 0) {                 // only wave 0 polls: 8 requests/period
        const int tgt = 32 * (t + 1);
        while (true) {
          int v = (lane < 8)
                    ? __hip_atomic_load(&arrive[lane * 16], __ATOMIC_RELAXED,
                                        __HIP_MEMORY_SCOPE_AGENT)
                    : tgt;
          if (__all(v >= tgt)) break;
        }
      }
      __atomic_signal_fence(__ATOMIC_SEQ_CST);
      __syncthreads();                 // epoch confirmed for whole WG
    } else {
      floatx2 hv = {h0, h1};
      floatx2 cv = {c0, c1};
      *reinterpret_cast<floatx2*>(out + ((size_t)gr * 512 + 511) * 1024 + u0) = hv;
      *reinterpret_cast<floatx2*>(out + (size_t)SEQ_N + (size_t)gr * 1024 + u0) = hv;
      *reinterpret_cast<floatx2*>(out + (size_t)SEQ_N + 65536 + (size_t)gr * 1024 + u0) = cv;
    }
  }
}

extern "C" void kernel_launch(void* const* d_in, const int* in_sizes, int n_in,
                              void* d_out, int out_size, void* d_ws, size_t ws_size,
                              hipStream_t stream) {
  const float* x    = (const float*)d_in[0];
  const float* W    = (const float*)d_in[1];
  const float* U    = (const float*)d_in[2];
  const float* bias = (const float*)d_in[3];
  float* out = (float*)d_out;
  char* ws = (char*)d_ws;

  short* upack = (short*)ws;                      // 10,485,760 B
  short* xbf   = (short*)(ws + 10485760);         // 16,777,216 B
  unsigned long long* hbuf = (unsigned long long*)(ws + 27262976); // 262,144 B
  int* arrive  = (int*)(ws + 27525120);           //     32,768 B
  (void)in_sizes; (void)n_in; (void)out_size; (void)ws_size;

  init_state<<<288, 256, 0, stream>>>((unsigned int*)hbuf, arrive);
  pack_weights<<<2560, 256, 0, stream>>>(W, U, upack);
  convert_x<<<4096, 256, 0, stream>>>(x, xbf);
  lstm_persist<<<NWG, 128, 0, stream>>>(xbf, upack, bias, hbuf, arrive, out);
}